// Round 10
// baseline (598.835 us; speedup 1.0000x reference)
//
#include <hip/hip_runtime.h>
#include <math.h>
#include <stdint.h>

// AIS estimator: N=1024 samples, B=128, DIM=DX=64, K=16 anneal steps, 3 leapfrog.
// Round 25: r24 + __launch_bounds__(256, 1) on k_main. r24 post-mortem:
// VGPR_Count=64 with >=64 f32 of live state and no scratch traffic =>
// compiler parked state in AGPRs and shuttles via v_accvgpr_read/write on a
// 96%-VALUBusy kernel (~2.3x inst bloat vs hand count). (256,1) grants the
// full VGPR budget -> state stays in arch VGPRs, shuttle gone. Codegen-only:
// absmax stays 0.0. (r20 lesson inverted: arg=1 RAISES the register cap.)
// Structure (r24): original-basis leapfrog, k_eig deleted. q' = q - mu:
//   g = bk*(f - q'A) - q' ;  w = wconst + q'.f - 0.5*q'.(q'A)
// y = q'A via validated f16-hi/lo 3-term MFMA (A packed as B-fragments);
// 3 matvecs/step (sub1 reuses prev w-eval's y); p consumed RAW (no rotation,
// no draw-splitting). y C-layout -> per-wave LDS transpose (pad-68).
// 4 launches: setup1, setup2x, k_main, reduce.

#define WS_A     0
#define WS_MU    4096
#define WS_C     12288
#define WS_XSQ   20480
#define WS_AMU   20608
#define WS_F     28800
#define WS_WC    36992
#define WS_V     37120
#define WS_LAM   41216
#define WS_FZ    41280
#define WS_VF    49472
#define WS_SLW   53568
#define WS_TOTAL (WS_SLW + 131072)

#define LOG2PI 1.8378770664093453f

typedef _Float16 half8_t __attribute__((ext_vector_type(8)));
typedef float f4_t __attribute__((ext_vector_type(4)));
typedef unsigned int uint4_t __attribute__((ext_vector_type(4)));

struct KParams {
  float beta[18];
  float dbeta[17];
  uint32_t fk0[16];
  uint32_t fk1[16];
};

__host__ __device__ static inline void threefry2x32(uint32_t ks0, uint32_t ks1,
                                                    uint32_t x0, uint32_t x1,
                                                    uint32_t& o0, uint32_t& o1) {
  uint32_t ks2 = ks0 ^ ks1 ^ 0x1BD11BDAu;
  x0 += ks0; x1 += ks1;
#define TFR(r) { x0 += x1; x1 = (x1 << (r)) | (x1 >> (32 - (r))); x1 ^= x0; }
  TFR(13) TFR(15) TFR(26) TFR(6)
  x0 += ks1; x1 += ks2 + 1u;
  TFR(17) TFR(29) TFR(16) TFR(24)
  x0 += ks2; x1 += ks0 + 2u;
  TFR(13) TFR(15) TFR(26) TFR(6)
  x0 += ks0; x1 += ks1 + 3u;
  TFR(17) TFR(29) TFR(16) TFR(24)
  x0 += ks1; x1 += ks2 + 4u;
  TFR(13) TFR(15) TFR(26) TFR(6)
  x0 += ks2; x1 += ks0 + 5u;
#undef TFR
  o0 = x0; o1 = x1;
}

__device__ __forceinline__ float u_from_bits(uint32_t bits) {
  const float LO = __uint_as_float(0xBF7FFFFFu);  // nextafter(-1,0) in f32
  float f = __uint_as_float((bits >> 9) | 0x3F800000u) - 1.0f;
  return fmaf(f, 2.0f, LO);
}

// XLA ErfInv32 (Giles); __logf variant validated r11-r14 (absmax = 1 bf16 ulp)
__device__ __forceinline__ float erfinv_f(float x) {
  float w = -__logf(fmaf(-x, x, 1.0f));
  float p;
  if (w < 5.0f) {
    w -= 2.5f;
    p = 2.81022636e-08f;
    p = fmaf(p, w, 3.43273939e-07f);
    p = fmaf(p, w, -3.5233877e-06f);
    p = fmaf(p, w, -4.39150654e-06f);
    p = fmaf(p, w, 0.00021858087f);
    p = fmaf(p, w, -0.00125372503f);
    p = fmaf(p, w, -0.00417768164f);
    p = fmaf(p, w, 0.246640727f);
    p = fmaf(p, w, 1.50140941f);
  } else {
    w = sqrtf(w) - 3.0f;
    p = -0.000200214257f;
    p = fmaf(p, w, 0.000100950558f);
    p = fmaf(p, w, 0.00134934322f);
    p = fmaf(p, w, -0.00367342844f);
    p = fmaf(p, w, 0.00573950773f);
    p = fmaf(p, w, -0.0076224613f);
    p = fmaf(p, w, 0.00943887047f);
    p = fmaf(p, w, 1.00167406f);
    p = fmaf(p, w, 2.83297682f);
  }
  return p * x;
}

// ---- setup1: A = Wdec Wdec^T ; mu[b][d] ; c[b][d] ; xsq[b]
__global__ void k_setup1(const float* __restrict__ x, const float* __restrict__ Wenc,
                         const float* __restrict__ Wdec, float* __restrict__ ws) {
  int t = blockIdx.x * 256 + threadIdx.x;
  if (t < 4096) {
    int i = t >> 6, j = t & 63;
    float s = 0;
    for (int e = 0; e < 64; ++e) s = fmaf(Wdec[i*64+e], Wdec[j*64+e], s);
    ws[WS_A + t] = s;
  } else if (t < 12288) {
    int u = t - 4096; int b = u >> 6, d = u & 63;
    float s = 0;
    for (int e = 0; e < 64; ++e) s = fmaf(x[b*64+e], Wenc[e*64+d], s);
    ws[WS_MU + u] = s;
  } else if (t < 20480) {
    int u = t - 12288; int b = u >> 6, d = u & 63;
    float s = 0;
    for (int e = 0; e < 64; ++e) s = fmaf(x[b*64+e], Wdec[d*64+e], s);
    ws[WS_C + u] = s;
  } else if (t < 20608) {
    int b = t - 20480;
    float s = 0;
    for (int e = 0; e < 64; ++e) s = fmaf(x[b*64+e], x[b*64+e], s);
    ws[WS_XSQ + b] = s;
  }
}

// ---- setup2x: blocks 0-31: F[b][d] = c - mu - (mu A)[d] (amu inline,
// same loop order as old setup2 -> bit-identical); blocks 32-35: pack A into
// f16 hi/lo MFMA B-fragments at WS_VF (same packing as V was; A symmetric);
// block 36: wconst[b] (amu inline, same order as old setup2+setup3).
__global__ void k_setup2x(float* __restrict__ ws) {
  int blk = blockIdx.x;
  if (blk < 32) {
    int t = blk * 256 + threadIdx.x;
    int b = t >> 6, d = t & 63;
    float s = 0;
    for (int m = 0; m < 64; ++m) s = fmaf(ws[WS_MU + b*64+m], ws[WS_A + m*64+d], s);
    ws[WS_F + t] = ws[WS_C + t] - ws[WS_MU + t] - s;
  } else if (blk < 36) {
    int idx = (blk - 32) * 256 + threadIdx.x;   // 0..1023
    int lane = idx & 63, F = idx >> 6;
    int t = F >> 3, kt = (F >> 2) & 1, nt = F & 3;
    int n = nt*16 + (lane & 15);
    int k0 = kt*32 + ((lane >> 4) & 3)*8;
    uint32_t out[4];
    for (int jj = 0; jj < 4; ++jj) {
      float v0 = ws[WS_A + (k0 + 2*jj    )*64 + n];
      float v1 = ws[WS_A + (k0 + 2*jj + 1)*64 + n];
      _Float16 h0, h1;
      if (t == 0) { h0 = (_Float16)v0; h1 = (_Float16)v1; }
      else {
        _Float16 a0 = (_Float16)v0, a1 = (_Float16)v1;
        h0 = (_Float16)(v0 - (float)a0);
        h1 = (_Float16)(v1 - (float)a1);
      }
      unsigned short u0 = __builtin_bit_cast(unsigned short, h0);
      unsigned short u1 = __builtin_bit_cast(unsigned short, h1);
      out[jj] = (uint32_t)u0 | ((uint32_t)u1 << 16);
    }
    uint32_t* dst = (uint32_t*)ws + WS_VF + idx*4;
    dst[0] = out[0]; dst[1] = out[1]; dst[2] = out[2]; dst[3] = out[3];
  } else {
    int b = threadIdx.x;
    if (b < 128) {
      float muc = 0, musq = 0, muamu = 0;
      for (int d = 0; d < 64; ++d) {
        float am = 0;
        for (int m = 0; m < 64; ++m) am = fmaf(ws[WS_MU + b*64+m], ws[WS_A + m*64+d], am);
        float mm = ws[WS_MU + b*64+d];
        muc   = fmaf(mm, ws[WS_C + b*64+d], muc);
        musq  = fmaf(mm, mm, musq);
        muamu = fmaf(mm, am, muamu);
      }
      ws[WS_WC + b] = -32.0f * LOG2PI - 0.5f * ws[WS_XSQ + b]
                      + muc - 0.5f * musq - 0.5f * muamu;
    }
  }
}

// ---- k_main macros ---------------------------------------------------------

#define DRAW(PC, IDX)                                                        \
  { uint32_t o0, o1;                                                         \
    threefry2x32(k0, k1, 0u, base + (IDX), o0, o1);                          \
    PC = 1.41421356f * erfinv_f(u_from_bits(o0 ^ o1)); }

#define SPLIT1(AH, AL, J, VV)                                                \
  { _Float16 hh = (_Float16)(VV); AH[J] = hh;                                \
    AL[J] = (_Float16)((VV) - (float)hh); }

#define FRAGB(T, KT, NT)                                                     \
  __builtin_bit_cast(half8_t, VF[(((T)*2+(KT))*4+(NT))*64 + lane])

#define ROT1(ZO, NT, AH0, AL0, AH1, AL1)                                     \
  { half8_t bh0 = FRAGB(0,0,NT), bh1 = FRAGB(0,1,NT);                        \
    half8_t bl0 = FRAGB(1,0,NT), bl1 = FRAGB(1,1,NT);                        \
    f4_t aa = {0.f, 0.f, 0.f, 0.f};                                          \
    aa = __builtin_amdgcn_mfma_f32_16x16x32_f16(AH0, bh0, aa, 0, 0, 0);      \
    aa = __builtin_amdgcn_mfma_f32_16x16x32_f16(AH1, bh1, aa, 0, 0, 0);      \
    aa = __builtin_amdgcn_mfma_f32_16x16x32_f16(AL0, bh0, aa, 0, 0, 0);      \
    aa = __builtin_amdgcn_mfma_f32_16x16x32_f16(AL1, bh1, aa, 0, 0, 0);      \
    aa = __builtin_amdgcn_mfma_f32_16x16x32_f16(AH0, bl0, aa, 0, 0, 0);      \
    aa = __builtin_amdgcn_mfma_f32_16x16x32_f16(AH1, bl1, aa, 0, 0, 0);      \
    ZO = aa; }

// transpose-write one C-layout tile (cols nt*16+dlow, rows 4 trajs) to LDS
#define TRY(NT, YC)                                                          \
  { int d_ = (NT)*16 + dlow;                                                 \
    TRS[(tq4+0)*68 + d_] = YC.x; TRS[(tq4+1)*68 + d_] = YC.y;                \
    TRS[(tq4+2)*68 + d_] = YC.z; TRS[(tq4+3)*68 + d_] = YC.w; }

// y = q'A : split q' -> 24 MFMA (3-term) -> LDS transpose -> y0..y3 (A-layout)
#define COMPY                                                                \
  { half8_t ah0, al0, ah1, al1;                                              \
    SPLIT1(ah0, al0, 0, qv0.x) SPLIT1(ah0, al0, 1, qv0.y)                    \
    SPLIT1(ah0, al0, 2, qv0.z) SPLIT1(ah0, al0, 3, qv0.w)                    \
    SPLIT1(ah0, al0, 4, qv1.x) SPLIT1(ah0, al0, 5, qv1.y)                    \
    SPLIT1(ah0, al0, 6, qv1.z) SPLIT1(ah0, al0, 7, qv1.w)                    \
    SPLIT1(ah1, al1, 0, qv2.x) SPLIT1(ah1, al1, 1, qv2.y)                    \
    SPLIT1(ah1, al1, 2, qv2.z) SPLIT1(ah1, al1, 3, qv2.w)                    \
    SPLIT1(ah1, al1, 4, qv3.x) SPLIT1(ah1, al1, 5, qv3.y)                    \
    SPLIT1(ah1, al1, 6, qv3.z) SPLIT1(ah1, al1, 7, qv3.w)                    \
    f4_t yC0, yC1, yC2, yC3;                                                 \
    ROT1(yC0, 0, ah0, al0, ah1, al1) ROT1(yC1, 1, ah0, al0, ah1, al1)        \
    ROT1(yC2, 2, ah0, al0, ah1, al1) ROT1(yC3, 3, ah0, al0, ah1, al1)        \
    TRY(0, yC0) TRY(1, yC1) TRY(2, yC2) TRY(3, yC3)                          \
    asm volatile("s_waitcnt lgkmcnt(0)" ::: "memory");                       \
    yv0 = *(const f4_t*)&TRS[trow + koff];                                   \
    yv1 = *(const f4_t*)&TRS[trow + koff + 4];                               \
    yv2 = *(const f4_t*)&TRS[trow + 32 + koff];                              \
    yv3 = *(const f4_t*)&TRS[trow + 32 + koff + 4];                          \
    asm volatile("" ::: "memory"); }

// leapfrog: g = bk*(f - y) - q' ; p += .025g (x2 if DBL) ; q' += .05p
#define LFV(QV, PV, FV, YV, DBL)                                             \
  { f4_t tt = FV - YV;                                                       \
    f4_t gg = __builtin_elementwise_fma(bk4, tt, -QV);                       \
    PV = __builtin_elementwise_fma(c025v, gg, PV);                           \
    if (DBL) PV = __builtin_elementwise_fma(c025v, gg, PV);                  \
    QV = __builtin_elementwise_fma(c005v, PV, QV); }
#define SUBSTEP(DBL)                                                         \
  LFV(qv0, pv0, fv0, yv0, DBL) LFV(qv1, pv1, fv1, yv1, DBL)                  \
  LFV(qv2, pv2, fv2, yv2, DBL) LFV(qv3, pv3, fv3, yv3, DBL)

// w = wconst + q'.f - 0.5*q'.y ; d-sum = 16 lane-local + lanes {16,32}
#define WEV(WOUT)                                                            \
  { f4_t s1v = fv0*qv0 + fv1*qv1 + fv2*qv2 + fv3*qv3;                        \
    f4_t s2v = qv0*yv0 + qv1*yv1 + qv2*yv2 + qv3*yv3;                        \
    f4_t vv = s1v - 0.5f*s2v;                                                \
    float r_ = vv.x + vv.y + vv.z + vv.w;                                    \
    r_ += __shfl_xor(r_, 16);                                                \
    r_ += __shfl_xor(r_, 32);                                                \
    WOUT = r_ + wcs; }

// ---- main: original-basis leapfrog; wave = 16 trajs; 4 waves/block.
// State in A-frag layout: traj = lane&15, d = (lane>>4)*8+[0..8) and +32.
// (256,1): full VGPR budget -> no AGPR shuttle (r25).
__global__ __launch_bounds__(256, 1) void k_main(const float* __restrict__ qn,
                                                 const float* __restrict__ ws,
                                                 float* __restrict__ slw_out,
                                                 KParams P) {
  __shared__ uint4_t VF[1024];        // 16 KB: A-hat f16 hi/lo B-fragments
  __shared__ float TR[4][16 * 68];    // 17 KB: per-wave transpose scratch
  const int tid = threadIdx.x;
  {
    const uint4_t* src = (const uint4_t*)((const uint32_t*)ws + WS_VF);
    for (int i = tid; i < 1024; i += 256) VF[i] = src[i];
  }
  __syncthreads();

  const int lane = tid & 63;
  const int wv = tid >> 6;
  const int trj = lane & 15;             // trajectory within wave
  const int g4 = lane >> 4;              // k-group
  const int koff = g4 * 8;               // d offset of this lane's components
  const int dlow = lane & 15;            // C-layout col (transpose write)
  const int tq4 = (lane >> 4) * 4;       // C-layout row base (transpose write)
  const int trow = trj * 68;             // transpose read row
  float* TRS = &TR[wv][0];
  const int trajBase = blockIdx.x * 64 + wv * 16;
  const uint32_t base = (uint32_t)(trajBase + trj) * 64u;  // RNG/state row
  const int b = (trajBase + trj) & 127;                    // batch col

  f4_t fv0, fv1, fv2, fv3;
  fv0 = *(const f4_t*)&ws[WS_F + b*64 + koff];
  fv1 = *(const f4_t*)&ws[WS_F + b*64 + koff + 4];
  fv2 = *(const f4_t*)&ws[WS_F + b*64 + 32 + koff];
  fv3 = *(const f4_t*)&ws[WS_F + b*64 + 32 + koff + 4];
  const float wcs = ws[WS_WC + b];
  const f4_t c025v = {0.025f, 0.025f, 0.025f, 0.025f};
  const f4_t c005v = {0.05f, 0.05f, 0.05f, 0.05f};

  f4_t qv0, qv1, qv2, qv3, pv0, pv1, pv2, pv3, yv0, yv1, yv2, yv3;
  float slw = 0.0f;

  // j = 0: q' = qn (A-layout load), y = q'A, w0
  {
    const float* qp = qn + (size_t)base;
    qv0 = *(const f4_t*)(qp + koff);
    qv1 = *(const f4_t*)(qp + koff + 4);
    qv2 = *(const f4_t*)(qp + 32 + koff);
    qv3 = *(const f4_t*)(qp + 32 + koff + 4);
  }
  COMPY
  {
    float w0;
    WEV(w0);
    slw = fmaf(P.dbeta[0], w0, slw);
  }

  for (int j = 1; j <= 16; ++j) {
    const float bk = P.beta[j];
    const f4_t bk4 = {bk, bk, bk, bk};
    const uint32_t k0 = P.fk0[j-1], k1 = P.fk1[j-1];
    // momentum resample: raw f32 draws, no rotation needed
    DRAW(pv0.x, koff + 0) DRAW(pv0.y, koff + 1)
    DRAW(pv0.z, koff + 2) DRAW(pv0.w, koff + 3)
    DRAW(pv1.x, koff + 4) DRAW(pv1.y, koff + 5)
    DRAW(pv1.z, koff + 6) DRAW(pv1.w, koff + 7)
    DRAW(pv2.x, 32 + koff + 0) DRAW(pv2.y, 32 + koff + 1)
    DRAW(pv2.z, 32 + koff + 2) DRAW(pv2.w, 32 + koff + 3)
    DRAW(pv3.x, 32 + koff + 4) DRAW(pv3.y, 32 + koff + 5)
    DRAW(pv3.z, 32 + koff + 6) DRAW(pv3.w, 32 + koff + 7)
    // leapfrog: sub1 reuses y from previous w-eval (same q')
    SUBSTEP(false)
    COMPY
    SUBSTEP(true)
    COMPY
    SUBSTEP(true)
    COMPY                       // y at final q' -> w-eval + next step's sub1
    float wj;
    WEV(wj);
    slw = fmaf(P.dbeta[j], wj, slw);
  }
  if (lane < 16) slw_out[trajBase + lane] = slw;
}

// ---- logsumexp over n per batch column b
__global__ void k_reduce(const float* __restrict__ slw, float* __restrict__ out) {
  __shared__ float red[256];
  int b = blockIdx.x, t = threadIdx.x;
  float v0 = slw[t*128 + b];
  float v1 = slw[(t+256)*128 + b];
  float v2 = slw[(t+512)*128 + b];
  float v3 = slw[(t+768)*128 + b];
  float m = fmaxf(fmaxf(v0, v1), fmaxf(v2, v3));
  red[t] = m; __syncthreads();
  for (int s = 128; s > 0; s >>= 1) {
    if (t < s) red[t] = fmaxf(red[t], red[t+s]);
    __syncthreads();
  }
  m = red[0]; __syncthreads();
  float sum = expf(v0 - m) + expf(v1 - m) + expf(v2 - m) + expf(v3 - m);
  red[t] = sum; __syncthreads();
  for (int s = 128; s > 0; s >>= 1) {
    if (t < s) red[t] += red[t+s];
    __syncthreads();
  }
  if (t == 0) out[b] = m + logf(red[0]) - 6.93147180559945309f;  // - log(1024)
}

extern "C" void kernel_launch(void* const* d_in, const int* in_sizes, int n_in,
                              void* d_out, int out_size, void* d_ws, size_t ws_size,
                              hipStream_t stream) {
  const float* x    = (const float*)d_in[0];
  const float* Wenc = (const float*)d_in[1];
  const float* Wdec = (const float*)d_in[2];
  const float* qn   = (const float*)d_in[3];
  // d_in[4] (p_noise) is dead: momentum fully resampled every anneal step.
  float* ws  = (float*)d_ws;
  float* out = (float*)d_out;
  if (ws_size < (size_t)WS_TOTAL * sizeof(float)) return;

  KParams P;
  double bb[18];
  for (int i = 0; i < 18; ++i) {
    double tt = (double)i / 17.0;
    bb[i] = 1.0 / (1.0 + exp(-(8.0 * tt - 4.0)));
  }
  for (int i = 0; i < 18; ++i) P.beta[i] = (float)((bb[i] - bb[0]) / (bb[17] - bb[0]));
  for (int j = 0; j <= 16; ++j) P.dbeta[j] = P.beta[j+1] - P.beta[j];
  for (int k = 1; k <= 16; ++k) {
    uint32_t a, c;
    threefry2x32(0u, 42u, 0u, (uint32_t)k, a, c);  // fold_in(key(42), k)
    P.fk0[k-1] = a; P.fk1[k-1] = c;
  }

  hipLaunchKernelGGL(k_setup1, dim3(81), dim3(256), 0, stream, x, Wenc, Wdec, ws);
  hipLaunchKernelGGL(k_setup2x, dim3(37), dim3(256), 0, stream, ws);
  hipLaunchKernelGGL(k_main, dim3(2048), dim3(256), 0, stream, qn, ws, ws + WS_SLW, P);
  hipLaunchKernelGGL(k_reduce, dim3(128), dim3(256), 0, stream, ws + WS_SLW, out);
}

// Round 11
// 583.767 us; speedup vs baseline: 1.0258x; 1.0258x over previous
//
#include <hip/hip_runtime.h>
#include <math.h>
#include <stdint.h>

// AIS estimator: N=1024 samples, B=128, DIM=DX=64, K=16 anneal steps, 3 leapfrog.
// Round 26: revert to r22 (best verified 572.8us, absmax 2.0) + fold setupfv
// into k_fused block 0 (flag-ordered), deleting one launch + gap.
// r24/r25 branch abandoned: original-basis leapfrog is ~200us worse (3
// matvecs+transposes/step; compiler AGPR-shuttle not fixable from source).
// Structure: setup1 -> k_fused -> k_main -> reduce (4 launches).
//  - k_fused: block 0 = eig (3 sweeps, r18 arithmetic) then POLLS setup2
//    completion flag (device atomics; only block 0 waits -> no deadlock) and
//    runs fz/VF/wconst reading V from its own LDS (identical bits).
//    blocks 1..nRng = RNG producer (staged steps + fractional, ws only;
//    pn staging dropped per r23: harness re-poison cost ~20us).
//    blocks nRng+1..+8 = setup2 (AMU, F) + threadfence + atomicAdd(flag).
//  - flag re-zeroed by k_setup1 every replay (graph-safe).
//  - k_main: r22 verbatim -- eigen-basis diagonal leapfrog, staged RNG
//    (dwordx4 + v_perm), pk-fma, __launch_bounds__(256) (VGPR~108; r20/r21:
//    never force min-waves, occupancy pinned by 64/128 VGPR steps).

#define WS_A     0
#define WS_MU    4096
#define WS_C     12288
#define WS_XSQ   20480
#define WS_AMU   20608
#define WS_F     28800
#define WS_WC    36992
#define WS_V     37120
#define WS_LAM   41216
#define WS_FZ    41280
#define WS_VF    49472
#define WS_SLW   53568
#define WS_FLG   (WS_SLW + 131072)   // int flag: setup2 completion count
#define WS_RNG   (WS_FLG + 64)       // u32 region, step-major: 8388608/step
#define WS_TOTAL WS_RNG
#define STEP_U32 8388608ull          // 524288 threads * 16 u32

#define LOG2PI 1.8378770664093453f

typedef _Float16 half8_t __attribute__((ext_vector_type(8)));
typedef float f4_t __attribute__((ext_vector_type(4)));
typedef unsigned int uint4_t __attribute__((ext_vector_type(4)));

struct KParams {
  float beta[18];
  float dbeta[17];
  uint32_t fk0[16];
  uint32_t fk1[16];
};

__host__ __device__ static inline void threefry2x32(uint32_t ks0, uint32_t ks1,
                                                    uint32_t x0, uint32_t x1,
                                                    uint32_t& o0, uint32_t& o1) {
  uint32_t ks2 = ks0 ^ ks1 ^ 0x1BD11BDAu;
  x0 += ks0; x1 += ks1;
#define TFR(r) { x0 += x1; x1 = (x1 << (r)) | (x1 >> (32 - (r))); x1 ^= x0; }
  TFR(13) TFR(15) TFR(26) TFR(6)
  x0 += ks1; x1 += ks2 + 1u;
  TFR(17) TFR(29) TFR(16) TFR(24)
  x0 += ks2; x1 += ks0 + 2u;
  TFR(13) TFR(15) TFR(26) TFR(6)
  x0 += ks0; x1 += ks1 + 3u;
  TFR(17) TFR(29) TFR(16) TFR(24)
  x0 += ks1; x1 += ks2 + 4u;
  TFR(13) TFR(15) TFR(26) TFR(6)
  x0 += ks2; x1 += ks0 + 5u;
#undef TFR
  o0 = x0; o1 = x1;
}

__device__ __forceinline__ float u_from_bits(uint32_t bits) {
  const float LO = __uint_as_float(0xBF7FFFFFu);  // nextafter(-1,0) in f32
  float f = __uint_as_float((bits >> 9) | 0x3F800000u) - 1.0f;
  return fmaf(f, 2.0f, LO);
}

// XLA ErfInv32 (Giles); __logf variant validated r11-r14 (absmax = 1 bf16 ulp)
__device__ __forceinline__ float erfinv_f(float x) {
  float w = -__logf(fmaf(-x, x, 1.0f));
  float p;
  if (w < 5.0f) {
    w -= 2.5f;
    p = 2.81022636e-08f;
    p = fmaf(p, w, 3.43273939e-07f);
    p = fmaf(p, w, -3.5233877e-06f);
    p = fmaf(p, w, -4.39150654e-06f);
    p = fmaf(p, w, 0.00021858087f);
    p = fmaf(p, w, -0.00125372503f);
    p = fmaf(p, w, -0.00417768164f);
    p = fmaf(p, w, 0.246640727f);
    p = fmaf(p, w, 1.50140941f);
  } else {
    w = sqrtf(w) - 3.0f;
    p = -0.000200214257f;
    p = fmaf(p, w, 0.000100950558f);
    p = fmaf(p, w, 0.00134934322f);
    p = fmaf(p, w, -0.00367342844f);
    p = fmaf(p, w, 0.00573950773f);
    p = fmaf(p, w, -0.0076224613f);
    p = fmaf(p, w, 0.00943887047f);
    p = fmaf(p, w, 1.00167406f);
    p = fmaf(p, w, 2.83297682f);
  }
  return p * x;
}

// ---- setup1: A = Wdec Wdec^T ; mu[b][d] ; c[b][d] ; xsq[b] ; flag = 0
__global__ void k_setup1(const float* __restrict__ x, const float* __restrict__ Wenc,
                         const float* __restrict__ Wdec, float* __restrict__ ws) {
  int t = blockIdx.x * 256 + threadIdx.x;
  if (t < 4096) {
    int i = t >> 6, j = t & 63;
    float s = 0;
    for (int e = 0; e < 64; ++e) s = fmaf(Wdec[i*64+e], Wdec[j*64+e], s);
    ws[WS_A + t] = s;
  } else if (t < 12288) {
    int u = t - 4096; int b = u >> 6, d = u & 63;
    float s = 0;
    for (int e = 0; e < 64; ++e) s = fmaf(x[b*64+e], Wenc[e*64+d], s);
    ws[WS_MU + u] = s;
  } else if (t < 20480) {
    int u = t - 12288; int b = u >> 6, d = u & 63;
    float s = 0;
    for (int e = 0; e < 64; ++e) s = fmaf(x[b*64+e], Wdec[d*64+e], s);
    ws[WS_C + u] = s;
  } else if (t < 20608) {
    int b = t - 20480;
    float s = 0;
    for (int e = 0; e < 64; ++e) s = fmaf(x[b*64+e], x[b*64+e], s);
    ws[WS_XSQ + b] = s;
  } else if (t == 20700) {
    ((int*)ws)[WS_FLG] = 0;    // setup2-completion flag (re-zero each replay)
  }
}

#define DRAW(PC, IDX)                                                        \
  { uint32_t o0, o1;                                                         \
    threefry2x32(k0, k1, 0u, base + (IDX), o0, o1);                          \
    PC = 1.41421356f * erfinv_f(u_from_bits(o0 ^ o1)); }

#define PACKD(DST, DD)                                                       \
  { _Float16 hh = (_Float16)(DD);                                            \
    _Float16 ll = (_Float16)((DD) - (float)hh);                              \
    DST = (uint32_t)__builtin_bit_cast(unsigned short, hh) |                 \
          ((uint32_t)__builtin_bit_cast(unsigned short, ll) << 16); }

// ---- k_fused: block 0 = eig (3 sweeps) + [poll flag] + fz/VF/wconst;
// blocks 1..nRng = RNG producer; blocks nRng+1..nRng+8 = setup2 (+flag).
#define EP 65
__global__ __launch_bounds__(1024) void k_fused(float* __restrict__ ws, KParams P,
                                                int nRng, int nS, int Lcut) {
  const int blk = blockIdx.x;
  const int tid = threadIdx.x;
  if (blk == 0) {
    // ---- cyclic Jacobi, 3 sweeps x 63 rounds, pitch 65 (r18 arithmetic)
    __shared__ float Am[64 * EP];
    __shared__ float Vm[64 * EP];
    __shared__ float cs_c[32], cs_s[32];
    __shared__ int ppu[32], ppv[32];
    for (int i = tid; i < 4096; i += 1024) {
      int r = i >> 6, c = i & 63;
      Am[r*EP + c] = ws[WS_A + i];
      Vm[r*EP + c] = (r == c) ? 1.0f : 0.0f;
    }
    const int pA = tid & 31;
    int uA = (pA == 0) ? 0 : pA;
    int vA = (pA == 0) ? 63 : (63 - pA);
    const int pV0 = tid >> 6;
    int uV0 = (pV0 == 0) ? 0 : pV0;
    int vV0 = (pV0 == 0) ? 63 : (63 - pV0);
    const int pV1 = 16 + pV0;
    int uV1 = pV1;
    int vV1 = 63 - pV1;
    __syncthreads();
    for (int sweep = 0; sweep < 3; ++sweep) {
      for (int r = 0; r < 63; ++r) {
        if (tid < 32) {
          float app = Am[uA*(EP+1)], aqq = Am[vA*(EP+1)], apq = Am[uA*EP+vA];
          float c = 1.0f, s = 0.0f;
          if (fabsf(apq) > 1e-30f) {
            float tau = (aqq - app) / (2.0f * apq);
            float t = copysignf(1.0f / (fabsf(tau) + sqrtf(fmaf(tau, tau, 1.0f))), tau);
            c = 1.0f / sqrtf(fmaf(t, t, 1.0f));
            s = t * c;
          }
          ppu[tid] = uA; ppv[tid] = vA; cs_c[tid] = c; cs_s[tid] = s;
        }
        __syncthreads();
        {
          int i = tid >> 5;
          int ui = ppu[i], vi = ppv[i];
          const int uj = uA, vj = vA;
          float ci = cs_c[i], si = cs_s[i], cj = cs_c[pA], sj = cs_s[pA];
          float a = Am[ui*EP+uj], bb = Am[ui*EP+vj];
          float d = Am[vi*EP+uj], e  = Am[vi*EP+vj];
          float r0u = ci*a  - si*d;
          float r1u = fmaf(si, a,  ci*d);
          float r0v = ci*bb - si*e;
          float r1v = fmaf(si, bb, ci*e);
          Am[ui*EP+uj] = cj*r0u - sj*r0v;
          Am[ui*EP+vj] = fmaf(sj, r0u, cj*r0v);
          Am[vi*EP+uj] = cj*r1u - sj*r1v;
          Am[vi*EP+vj] = fmaf(sj, r1u, cj*r1v);
        }
        {
          const int k = tid & 63;
          {
            float c2 = cs_c[pV0], s2 = cs_s[pV0];
            float vu = Vm[k*EP+uV0], vv = Vm[k*EP+vV0];
            Vm[k*EP+uV0] = c2*vu - s2*vv;
            Vm[k*EP+vV0] = fmaf(s2, vu, c2*vv);
          }
          {
            float c2 = cs_c[pV1], s2 = cs_s[pV1];
            float vu = Vm[k*EP+uV1], vv = Vm[k*EP+vV1];
            Vm[k*EP+uV1] = c2*vu - s2*vv;
            Vm[k*EP+vV1] = fmaf(s2, vu, c2*vv);
          }
        }
        uA  = (uA  == 0) ? 0 : ((uA  == 63) ? 1 : uA  + 1);
        vA  = (vA  == 63) ? 1 : vA  + 1;
        uV0 = (uV0 == 0) ? 0 : ((uV0 == 63) ? 1 : uV0 + 1);
        vV0 = (vV0 == 63) ? 1 : vV0 + 1;
        uV1 = (uV1 == 63) ? 1 : uV1 + 1;
        vV1 = (vV1 == 63) ? 1 : vV1 + 1;
        __syncthreads();
      }
    }
    if (tid < 64) ws[WS_LAM + tid] = Am[tid*(EP+1)];
    // ---- wait for setup2 blocks (only block 0 waits -> no deadlock)
    if (tid == 0) {
      while (atomicAdd((int*)ws + WS_FLG, 0) < 8) { }
    }
    __syncthreads();
    __threadfence();
    // ---- fz = F V (V from LDS, identical bits; FMA order = old setupfv)
    for (int t2 = tid; t2 < 8192; t2 += 1024) {
      int b = t2 >> 6, d = t2 & 63;
      float s = 0;
      for (int m = 0; m < 64; ++m) s = fmaf(ws[WS_F + b*64+m], Vm[m*EP+d], s);
      ws[WS_FZ + t2] = s;
    }
    // ---- pack V into f16 hi/lo MFMA B-fragments (frag layout as before)
    {
      int idx = tid;                     // 0..1023
      int lane = idx & 63, Fr = idx >> 6;
      int t = Fr >> 3, kt = (Fr >> 2) & 1, nt = Fr & 3;
      int n = nt*16 + (lane & 15);
      int k0 = kt*32 + ((lane >> 4) & 3)*8;
      uint32_t out[4];
      for (int jj = 0; jj < 4; ++jj) {
        float v0 = Vm[(k0 + 2*jj    )*EP + n];
        float v1 = Vm[(k0 + 2*jj + 1)*EP + n];
        _Float16 h0, h1;
        if (t == 0) { h0 = (_Float16)v0; h1 = (_Float16)v1; }
        else {
          _Float16 a0 = (_Float16)v0, a1 = (_Float16)v1;
          h0 = (_Float16)(v0 - (float)a0);
          h1 = (_Float16)(v1 - (float)a1);
        }
        unsigned short u0 = __builtin_bit_cast(unsigned short, h0);
        unsigned short u1 = __builtin_bit_cast(unsigned short, h1);
        out[jj] = (uint32_t)u0 | ((uint32_t)u1 << 16);
      }
      uint32_t* dst = (uint32_t*)ws + WS_VF + idx*4;
      dst[0] = out[0]; dst[1] = out[1]; dst[2] = out[2]; dst[3] = out[3];
    }
    // ---- wconst[b] (same expression order as old setup3)
    if (tid < 128) {
      int b = tid;
      float muc = 0, musq = 0, muamu = 0;
      for (int d = 0; d < 64; ++d) {
        float m = ws[WS_MU + b*64+d];
        muc   = fmaf(m, ws[WS_C + b*64+d], muc);
        musq  = fmaf(m, m, musq);
        muamu = fmaf(m, ws[WS_AMU + b*64+d], muamu);
      }
      ws[WS_WC + b] = -32.0f * LOG2PI - 0.5f * ws[WS_XSQ + b]
                      + muc - 0.5f * musq - 0.5f * muamu;
    }
  } else if (blk <= nRng) {
    // ---- RNG producer: exact k_main DRAW+SPLIT, packed f16hi|f16lo u32,
    // step-major layout. Threads L < Lcut stage one extra (fractional) step.
    const int L = (blk - 1) * 1024 + tid;
    const int bI = L >> 8, t256 = L & 255;
    const int wv = t256 >> 6, lane = t256 & 63;
    const int cw = lane & 15, g4 = lane >> 4;
    const int koff = g4 * 8;
    const int trajBase = bI * 64 + wv * 16;
    const uint32_t base = (uint32_t)(trajBase + cw) * 64u;
    uint32_t* wsu = (uint32_t*)ws;
    const int nSteps = nS + ((nS < 16 && L < Lcut) ? 1 : 0);
    for (int j = 1; j <= nSteps; ++j) {
      const uint32_t k0 = P.fk0[j-1], k1 = P.fk1[j-1];
      uint32_t ov[16];
#pragma unroll
      for (int i = 0; i < 8; ++i) { float dd; DRAW(dd, koff + i) PACKD(ov[i], dd) }
#pragma unroll
      for (int i = 0; i < 8; ++i) { float dd; DRAW(dd, 32 + koff + i) PACKD(ov[8+i], dd) }
      uint4_t* wr = (uint4_t*)(wsu + WS_RNG + (size_t)(j-1)*STEP_U32 + (size_t)L*16u);
      wr[0] = (uint4_t){ov[0], ov[1], ov[2], ov[3]};
      wr[1] = (uint4_t){ov[4], ov[5], ov[6], ov[7]};
      wr[2] = (uint4_t){ov[8], ov[9], ov[10], ov[11]};
      wr[3] = (uint4_t){ov[12], ov[13], ov[14], ov[15]};
    }
  } else {
    // ---- setup2: amu[b][d] = (mu A)[d] ; f[b][d] = c - mu - amu ; flag++
    int t = (blk - 1 - nRng) * 1024 + tid;
    if (t < 8192) {
      int b = t >> 6, d = t & 63;
      float s = 0;
      for (int m = 0; m < 64; ++m) s = fmaf(ws[WS_MU + b*64+m], ws[WS_A + m*64+d], s);
      ws[WS_AMU + t] = s;
      ws[WS_F + t] = ws[WS_C + t] - ws[WS_MU + t] - s;
    }
    __syncthreads();
    if (tid == 0) {
      __threadfence();
      atomicAdd((int*)ws + WS_FLG, 1);
    }
  }
}

// ---- k_main hot-loop macros ------------------------------------------------

#define SPLIT1(AH, AL, J, VV)                                                \
  { _Float16 hh = (_Float16)(VV); AH[J] = hh;                                \
    AL[J] = (_Float16)((VV) - (float)hh); }

#define DRAWSPLIT8(AH, AL, KB)                                               \
  { float dd;                                                                \
    DRAW(dd, (KB)+0) SPLIT1(AH, AL, 0, dd)                                   \
    DRAW(dd, (KB)+1) SPLIT1(AH, AL, 1, dd)                                   \
    DRAW(dd, (KB)+2) SPLIT1(AH, AL, 2, dd)                                   \
    DRAW(dd, (KB)+3) SPLIT1(AH, AL, 3, dd)                                   \
    DRAW(dd, (KB)+4) SPLIT1(AH, AL, 4, dd)                                   \
    DRAW(dd, (KB)+5) SPLIT1(AH, AL, 5, dd)                                   \
    DRAW(dd, (KB)+6) SPLIT1(AH, AL, 6, dd)                                   \
    DRAW(dd, (KB)+7) SPLIT1(AH, AL, 7, dd) }

#define FRAGB(T, KT, NT)                                                     \
  __builtin_bit_cast(half8_t, VF[(((T)*2+(KT))*4+(NT))*64 + lane])

#define ROT1(ZO, NT, AH0, AL0, AH1, AL1)                                     \
  { half8_t bh0 = FRAGB(0,0,NT), bh1 = FRAGB(0,1,NT);                        \
    half8_t bl0 = FRAGB(1,0,NT), bl1 = FRAGB(1,1,NT);                        \
    f4_t aa = {0.f, 0.f, 0.f, 0.f};                                          \
    aa = __builtin_amdgcn_mfma_f32_16x16x32_f16(AH0, bh0, aa, 0, 0, 0);      \
    aa = __builtin_amdgcn_mfma_f32_16x16x32_f16(AH1, bh1, aa, 0, 0, 0);      \
    aa = __builtin_amdgcn_mfma_f32_16x16x32_f16(AL0, bh0, aa, 0, 0, 0);      \
    aa = __builtin_amdgcn_mfma_f32_16x16x32_f16(AL1, bh1, aa, 0, 0, 0);      \
    aa = __builtin_amdgcn_mfma_f32_16x16x32_f16(AH0, bl0, aa, 0, 0, 0);      \
    aa = __builtin_amdgcn_mfma_f32_16x16x32_f16(AH1, bl1, aa, 0, 0, 0);      \
    ZO = aa; }

#define ROTATE4(O0, O1, O2, O3, AH0, AL0, AH1, AL1)                          \
  ROT1(O0, 0, AH0, AL0, AH1, AL1) ROT1(O1, 1, AH0, AL0, AH1, AL1)            \
  ROT1(O2, 2, AH0, AL0, AH1, AL1) ROT1(O3, 3, AH0, AL0, AH1, AL1)

// vectorized leapfrog: v_pk_fma_f32 path, IEEE-identical per component
#define LF4V(ZV, PV, NLM, FV, DBL)                                           \
  { f4_t gg = __builtin_elementwise_fma(bk4,                                 \
        __builtin_elementwise_fma(NLM, ZV, FV), -ZV);                        \
    PV = __builtin_elementwise_fma(c025v, gg, PV);                           \
    if (DBL) PV = __builtin_elementwise_fma(c025v, gg, PV);                  \
    ZV = __builtin_elementwise_fma(c005v, PV, ZV); }
#define SUBSTEPV(DBL)                                                        \
  LF4V(z0, pz0, nlm0, fzv0, DBL) LF4V(z1, pz1, nlm1, fzv1, DBL)              \
  LF4V(z2, pz2, nlm2, fzv2, DBL) LF4V(z3, pz3, nlm3, fzv3, DBL)

#define W_EVALN(WOUT)                                                        \
  { f4_t s1 = fzv0*z0 + fzv1*z1 + fzv2*z2 + fzv3*z3;                         \
    f4_t s2 = (lmS0*z0)*z0 + (lmS1*z1)*z1 + (lmS2*z2)*z2 + (lmS3*z3)*z3;     \
    f4_t vv = s1 - 0.5f*s2;                                                  \
    float r0 = vv.x, r1 = vv.y, r2 = vv.z, r3 = vv.w;                        \
    r0 += __shfl_xor(r0, 1); r1 += __shfl_xor(r1, 1);                        \
    r2 += __shfl_xor(r2, 1); r3 += __shfl_xor(r3, 1);                        \
    r0 += __shfl_xor(r0, 2); r1 += __shfl_xor(r1, 2);                        \
    r2 += __shfl_xor(r2, 2); r3 += __shfl_xor(r3, 2);                        \
    r0 += __shfl_xor(r0, 4); r1 += __shfl_xor(r1, 4);                        \
    r2 += __shfl_xor(r2, 4); r3 += __shfl_xor(r3, 4);                        \
    r0 += __shfl_xor(r0, 8); r1 += __shfl_xor(r1, 8);                        \
    r2 += __shfl_xor(r2, 8); r3 += __shfl_xor(r3, 8);                        \
    float wsel = (cw == 0) ? r0 : ((cw == 1) ? r1 : ((cw == 2) ? r2 : r3));  \
    WOUT = wsel + wcs; }

#define PLO 0x05040100u
#define PHI 0x07060302u

// ---- main: MFMA rotation; wave = 16 trajs; 4 waves/block, 2048 blocks.
__global__ __launch_bounds__(256) void k_main(const float* __restrict__ qn,
                                              const float* __restrict__ ws,
                                              float* __restrict__ slw_out,
                                              KParams P, int nS, int Lcut) {
  __shared__ uint4_t VF[1024];   // 16 KB: V f16 hi/lo B-fragments
  const int tid = threadIdx.x;
  {
    const uint4_t* src = (const uint4_t*)((const uint32_t*)ws + WS_VF);
    for (int i = tid; i < 1024; i += 256) VF[i] = src[i];
  }
  __syncthreads();

  const int lane = tid & 63;
  const int wv = tid >> 6;
  const int cw = lane & 15;              // MFMA col; also A-operand row m
  const int g4 = lane >> 4;              // quad id
  const int koff = g4 * 8;               // A-fragment k offset
  const int trajBase = blockIdx.x * 64 + wv * 16;
  const uint32_t base = (uint32_t)(trajBase + cw) * 64u;   // RNG row base
  const int Lme = blockIdx.x * 256 + tid;                  // staged-RNG row

  const int b0 = (trajBase + g4*4 + 0) & 127;
  const int b1 = (trajBase + g4*4 + 1) & 127;
  const int b2 = (trajBase + g4*4 + 2) & 127;
  const int b3 = (trajBase + g4*4 + 3) & 127;
  f4_t fzv0, fzv1, fzv2, fzv3;
  fzv0.x = ws[WS_FZ + b0*64 + cw];      fzv0.y = ws[WS_FZ + b1*64 + cw];
  fzv0.z = ws[WS_FZ + b2*64 + cw];      fzv0.w = ws[WS_FZ + b3*64 + cw];
  fzv1.x = ws[WS_FZ + b0*64 + 16 + cw]; fzv1.y = ws[WS_FZ + b1*64 + 16 + cw];
  fzv1.z = ws[WS_FZ + b2*64 + 16 + cw]; fzv1.w = ws[WS_FZ + b3*64 + 16 + cw];
  fzv2.x = ws[WS_FZ + b0*64 + 32 + cw]; fzv2.y = ws[WS_FZ + b1*64 + 32 + cw];
  fzv2.z = ws[WS_FZ + b2*64 + 32 + cw]; fzv2.w = ws[WS_FZ + b3*64 + 32 + cw];
  fzv3.x = ws[WS_FZ + b0*64 + 48 + cw]; fzv3.y = ws[WS_FZ + b1*64 + 48 + cw];
  fzv3.z = ws[WS_FZ + b2*64 + 48 + cw]; fzv3.w = ws[WS_FZ + b3*64 + 48 + cw];
  const float lmS0 = ws[WS_LAM + cw];
  const float lmS1 = ws[WS_LAM + 16 + cw];
  const float lmS2 = ws[WS_LAM + 32 + cw];
  const float lmS3 = ws[WS_LAM + 48 + cw];
  const float wcs = ws[WS_WC + ((trajBase + g4*4 + (cw & 3)) & 127)];
  const f4_t nlm0 = {-lmS0, -lmS0, -lmS0, -lmS0};
  const f4_t nlm1 = {-lmS1, -lmS1, -lmS1, -lmS1};
  const f4_t nlm2 = {-lmS2, -lmS2, -lmS2, -lmS2};
  const f4_t nlm3 = {-lmS3, -lmS3, -lmS3, -lmS3};
  const f4_t c025v = {0.025f, 0.025f, 0.025f, 0.025f};
  const f4_t c005v = {0.05f, 0.05f, 0.05f, 0.05f};

  f4_t z0, z1, z2, z3, pz0, pz1, pz2, pz3;
  float slw = 0.0f;

  // j = 0: z0 = qn . V  (qn read at A-fragment positions; f16 3-term split)
  {
    const float* qp = qn + (size_t)base;
    f4_t qa = *(const f4_t*)(qp + koff);
    f4_t qb = *(const f4_t*)(qp + koff + 4);
    f4_t qc = *(const f4_t*)(qp + 32 + koff);
    f4_t qd = *(const f4_t*)(qp + 32 + koff + 4);
    half8_t ah0, al0, ah1, al1;
    SPLIT1(ah0, al0, 0, qa.x) SPLIT1(ah0, al0, 1, qa.y)
    SPLIT1(ah0, al0, 2, qa.z) SPLIT1(ah0, al0, 3, qa.w)
    SPLIT1(ah0, al0, 4, qb.x) SPLIT1(ah0, al0, 5, qb.y)
    SPLIT1(ah0, al0, 6, qb.z) SPLIT1(ah0, al0, 7, qb.w)
    SPLIT1(ah1, al1, 0, qc.x) SPLIT1(ah1, al1, 1, qc.y)
    SPLIT1(ah1, al1, 2, qc.z) SPLIT1(ah1, al1, 3, qc.w)
    SPLIT1(ah1, al1, 4, qd.x) SPLIT1(ah1, al1, 5, qd.y)
    SPLIT1(ah1, al1, 6, qd.z) SPLIT1(ah1, al1, 7, qd.w)
    ROTATE4(z0, z1, z2, z3, ah0, al0, ah1, al1)
  }
  {
    float w0;
    W_EVALN(w0);
    slw = fmaf(P.dbeta[0], w0, slw);
  }

  for (int j = 1; j <= 16; ++j) {
    const float bk = P.beta[j];
    const f4_t bk4 = {bk, bk, bk, bk};
    half8_t ah0, al0, ah1, al1;
    if (j <= nS || (j == nS + 1 && Lme < Lcut)) {
      // staged: load packed f16hi|f16lo draws (step-major), unpack via v_perm
      const uint32_t* rp = (const uint32_t*)ws + WS_RNG
                         + (size_t)(j-1)*STEP_U32 + (size_t)Lme*16u;
      const uint4_t* rr = (const uint4_t*)rp;
      uint4_t q0 = rr[0], q1 = rr[1], q2 = rr[2], q3 = rr[3];
      uint4_t uh0 = { __builtin_amdgcn_perm(q0.y, q0.x, PLO),
                      __builtin_amdgcn_perm(q0.w, q0.z, PLO),
                      __builtin_amdgcn_perm(q1.y, q1.x, PLO),
                      __builtin_amdgcn_perm(q1.w, q1.z, PLO) };
      uint4_t ul0 = { __builtin_amdgcn_perm(q0.y, q0.x, PHI),
                      __builtin_amdgcn_perm(q0.w, q0.z, PHI),
                      __builtin_amdgcn_perm(q1.y, q1.x, PHI),
                      __builtin_amdgcn_perm(q1.w, q1.z, PHI) };
      uint4_t uh1 = { __builtin_amdgcn_perm(q2.y, q2.x, PLO),
                      __builtin_amdgcn_perm(q2.w, q2.z, PLO),
                      __builtin_amdgcn_perm(q3.y, q3.x, PLO),
                      __builtin_amdgcn_perm(q3.w, q3.z, PLO) };
      uint4_t ul1 = { __builtin_amdgcn_perm(q2.y, q2.x, PHI),
                      __builtin_amdgcn_perm(q2.w, q2.z, PHI),
                      __builtin_amdgcn_perm(q3.y, q3.x, PHI),
                      __builtin_amdgcn_perm(q3.w, q3.z, PHI) };
      ah0 = __builtin_bit_cast(half8_t, uh0);
      al0 = __builtin_bit_cast(half8_t, ul0);
      ah1 = __builtin_bit_cast(half8_t, uh1);
      al1 = __builtin_bit_cast(half8_t, ul1);
    } else {
      const uint32_t k0 = P.fk0[j-1], k1 = P.fk1[j-1];
      DRAWSPLIT8(ah0, al0, koff)
      DRAWSPLIT8(ah1, al1, 32 + koff)
    }
    ROTATE4(pz0, pz1, pz2, pz3, ah0, al0, ah1, al1)   // pz = p . V
    SUBSTEPV(false)
    SUBSTEPV(true)
    SUBSTEPV(true)
    float wj;
    W_EVALN(wj);
    slw = fmaf(P.dbeta[j], wj, slw);
  }
  if (cw < 4) slw_out[trajBase + g4*4 + cw] = slw;
}

// ---- logsumexp over n per batch column b
__global__ void k_reduce(const float* __restrict__ slw, float* __restrict__ out) {
  __shared__ float red[256];
  int b = blockIdx.x, t = threadIdx.x;
  float v0 = slw[t*128 + b];
  float v1 = slw[(t+256)*128 + b];
  float v2 = slw[(t+512)*128 + b];
  float v3 = slw[(t+768)*128 + b];
  float m = fmaxf(fmaxf(v0, v1), fmaxf(v2, v3));
  red[t] = m; __syncthreads();
  for (int s = 128; s > 0; s >>= 1) {
    if (t < s) red[t] = fmaxf(red[t], red[t+s]);
    __syncthreads();
  }
  m = red[0]; __syncthreads();
  float sum = expf(v0 - m) + expf(v1 - m) + expf(v2 - m) + expf(v3 - m);
  red[t] = sum; __syncthreads();
  for (int s = 128; s > 0; s >>= 1) {
    if (t < s) red[t] += red[t+s];
    __syncthreads();
  }
  if (t == 0) out[b] = m + logf(red[0]) - 6.93147180559945309f;  // - log(1024)
}

extern "C" void kernel_launch(void* const* d_in, const int* in_sizes, int n_in,
                              void* d_out, int out_size, void* d_ws, size_t ws_size,
                              hipStream_t stream) {
  const float* x    = (const float*)d_in[0];
  const float* Wenc = (const float*)d_in[1];
  const float* Wdec = (const float*)d_in[2];
  const float* qn   = (const float*)d_in[3];
  // d_in[4] (p_noise) is dead (momentum fully resampled) but NOT used for
  // staging: dirtying an input costs ~20us harness re-poison (r23).
  float* ws  = (float*)d_ws;
  float* out = (float*)d_out;
  if (ws_size < (size_t)WS_TOTAL * sizeof(float)) return;

  // staged-RNG step count from available workspace (33.55 MB per step),
  // plus fractional staging of the next step with the leftover.
  size_t avail_u32 = ws_size / 4;
  int nS = 0, Lcut = 0;
  if (avail_u32 > (size_t)WS_RNG) {
    size_t r = avail_u32 - (size_t)WS_RNG;
    nS = (int)(r / STEP_U32);
    if (nS > 16) nS = 16;
    if (nS < 16) {
      size_t rem = r - (size_t)nS * STEP_U32;
      size_t lc = (rem / 16) & ~(size_t)63;       // wave-aligned thread count
      if (lc > 524288) lc = 524288;
      Lcut = (int)lc;
    }
  }
  const int nRng = (nS > 0 || Lcut > 0) ? 512 : 0;

  KParams P;
  double bb[18];
  for (int i = 0; i < 18; ++i) {
    double tt = (double)i / 17.0;
    bb[i] = 1.0 / (1.0 + exp(-(8.0 * tt - 4.0)));
  }
  for (int i = 0; i < 18; ++i) P.beta[i] = (float)((bb[i] - bb[0]) / (bb[17] - bb[0]));
  for (int j = 0; j <= 16; ++j) P.dbeta[j] = P.beta[j+1] - P.beta[j];
  for (int k = 1; k <= 16; ++k) {
    uint32_t a, c;
    threefry2x32(0u, 42u, 0u, (uint32_t)k, a, c);  // fold_in(key(42), k)
    P.fk0[k-1] = a; P.fk1[k-1] = c;
  }

  hipLaunchKernelGGL(k_setup1, dim3(81), dim3(256), 0, stream, x, Wenc, Wdec, ws);
  hipLaunchKernelGGL(k_fused, dim3(1 + nRng + 8), dim3(1024), 0, stream, ws, P, nRng, nS, Lcut);
  hipLaunchKernelGGL(k_main, dim3(2048), dim3(256), 0, stream, qn, ws, ws + WS_SLW, P, nS, Lcut);
  hipLaunchKernelGGL(k_reduce, dim3(128), dim3(256), 0, stream, ws + WS_SLW, out);
}

// Round 12
// 565.093 us; speedup vs baseline: 1.0597x; 1.0330x over previous
//
#include <hip/hip_runtime.h>
#include <math.h>
#include <stdint.h>

// AIS estimator: N=1024 samples, B=128, DIM=DX=64, K=16 anneal steps, 3 leapfrog.
// Round 27: r22 structure + corrected launch-fold. r26's mistake: fz (524K
// global-load dots) serialized onto block 0's CU after eig (+10-15us). Fix:
// tail work (fz/VF/wconst) runs on the EIGHT setup2 blocks, gated by two
// flags: flagF (all F written, 8 blocks) and flagV (block 0 wrote V+LAM).
// Block 0 = eig only (critical path shorter than r22). Waiters are the
// last-dispatched blocks and wait only on block 0 -> no deadlock; RNG blocks
// release CUs ~50us in. Identical expressions/order -> absmax 2.0.
// 3 launches: setup1, k_fused, k_main, reduce (setupfv launch deleted).
//  - RNG producer: staged steps + fractional (ws only; r23: pn staging costs
//    ~20us harness re-poison -> not used).
//  - k_main: r22 verbatim -- eigen-basis diagonal leapfrog, staged RNG
//    (dwordx4 + v_perm), pk-fma, __launch_bounds__(256), VGPR~108.

#define WS_A     0
#define WS_MU    4096
#define WS_C     12288
#define WS_XSQ   20480
#define WS_AMU   20608
#define WS_F     28800
#define WS_WC    36992
#define WS_V     37120
#define WS_LAM   41216
#define WS_FZ    41280
#define WS_VF    49472
#define WS_SLW   53568
#define WS_FLG   (WS_SLW + 131072)   // int[0]=flagF (setup2 done), int[1]=flagV
#define WS_RNG   (WS_FLG + 64)       // u32 region, step-major: 8388608/step
#define WS_TOTAL WS_RNG
#define STEP_U32 8388608ull          // 524288 threads * 16 u32

#define LOG2PI 1.8378770664093453f

typedef _Float16 half8_t __attribute__((ext_vector_type(8)));
typedef float f4_t __attribute__((ext_vector_type(4)));
typedef unsigned int uint4_t __attribute__((ext_vector_type(4)));

struct KParams {
  float beta[18];
  float dbeta[17];
  uint32_t fk0[16];
  uint32_t fk1[16];
};

__host__ __device__ static inline void threefry2x32(uint32_t ks0, uint32_t ks1,
                                                    uint32_t x0, uint32_t x1,
                                                    uint32_t& o0, uint32_t& o1) {
  uint32_t ks2 = ks0 ^ ks1 ^ 0x1BD11BDAu;
  x0 += ks0; x1 += ks1;
#define TFR(r) { x0 += x1; x1 = (x1 << (r)) | (x1 >> (32 - (r))); x1 ^= x0; }
  TFR(13) TFR(15) TFR(26) TFR(6)
  x0 += ks1; x1 += ks2 + 1u;
  TFR(17) TFR(29) TFR(16) TFR(24)
  x0 += ks2; x1 += ks0 + 2u;
  TFR(13) TFR(15) TFR(26) TFR(6)
  x0 += ks0; x1 += ks1 + 3u;
  TFR(17) TFR(29) TFR(16) TFR(24)
  x0 += ks1; x1 += ks2 + 4u;
  TFR(13) TFR(15) TFR(26) TFR(6)
  x0 += ks2; x1 += ks0 + 5u;
#undef TFR
  o0 = x0; o1 = x1;
}

__device__ __forceinline__ float u_from_bits(uint32_t bits) {
  const float LO = __uint_as_float(0xBF7FFFFFu);  // nextafter(-1,0) in f32
  float f = __uint_as_float((bits >> 9) | 0x3F800000u) - 1.0f;
  return fmaf(f, 2.0f, LO);
}

// XLA ErfInv32 (Giles); __logf variant validated r11-r14 (absmax = 1 bf16 ulp)
__device__ __forceinline__ float erfinv_f(float x) {
  float w = -__logf(fmaf(-x, x, 1.0f));
  float p;
  if (w < 5.0f) {
    w -= 2.5f;
    p = 2.81022636e-08f;
    p = fmaf(p, w, 3.43273939e-07f);
    p = fmaf(p, w, -3.5233877e-06f);
    p = fmaf(p, w, -4.39150654e-06f);
    p = fmaf(p, w, 0.00021858087f);
    p = fmaf(p, w, -0.00125372503f);
    p = fmaf(p, w, -0.00417768164f);
    p = fmaf(p, w, 0.246640727f);
    p = fmaf(p, w, 1.50140941f);
  } else {
    w = sqrtf(w) - 3.0f;
    p = -0.000200214257f;
    p = fmaf(p, w, 0.000100950558f);
    p = fmaf(p, w, 0.00134934322f);
    p = fmaf(p, w, -0.00367342844f);
    p = fmaf(p, w, 0.00573950773f);
    p = fmaf(p, w, -0.0076224613f);
    p = fmaf(p, w, 0.00943887047f);
    p = fmaf(p, w, 1.00167406f);
    p = fmaf(p, w, 2.83297682f);
  }
  return p * x;
}

// ---- setup1: A = Wdec Wdec^T ; mu[b][d] ; c[b][d] ; xsq[b] ; flags = 0
__global__ void k_setup1(const float* __restrict__ x, const float* __restrict__ Wenc,
                         const float* __restrict__ Wdec, float* __restrict__ ws) {
  int t = blockIdx.x * 256 + threadIdx.x;
  if (t < 4096) {
    int i = t >> 6, j = t & 63;
    float s = 0;
    for (int e = 0; e < 64; ++e) s = fmaf(Wdec[i*64+e], Wdec[j*64+e], s);
    ws[WS_A + t] = s;
  } else if (t < 12288) {
    int u = t - 4096; int b = u >> 6, d = u & 63;
    float s = 0;
    for (int e = 0; e < 64; ++e) s = fmaf(x[b*64+e], Wenc[e*64+d], s);
    ws[WS_MU + u] = s;
  } else if (t < 20480) {
    int u = t - 12288; int b = u >> 6, d = u & 63;
    float s = 0;
    for (int e = 0; e < 64; ++e) s = fmaf(x[b*64+e], Wdec[d*64+e], s);
    ws[WS_C + u] = s;
  } else if (t < 20608) {
    int b = t - 20480;
    float s = 0;
    for (int e = 0; e < 64; ++e) s = fmaf(x[b*64+e], x[b*64+e], s);
    ws[WS_XSQ + b] = s;
  } else if (t == 20700) {
    ((int*)ws)[WS_FLG] = 0;        // flagF: setup2 completion count
  } else if (t == 20701) {
    ((int*)ws)[WS_FLG + 1] = 0;    // flagV: eig V+LAM written
  }
}

#define DRAW(PC, IDX)                                                        \
  { uint32_t o0, o1;                                                         \
    threefry2x32(k0, k1, 0u, base + (IDX), o0, o1);                          \
    PC = 1.41421356f * erfinv_f(u_from_bits(o0 ^ o1)); }

#define PACKD(DST, DD)                                                       \
  { _Float16 hh = (_Float16)(DD);                                            \
    _Float16 ll = (_Float16)((DD) - (float)hh);                              \
    DST = (uint32_t)__builtin_bit_cast(unsigned short, hh) |                 \
          ((uint32_t)__builtin_bit_cast(unsigned short, ll) << 16); }

// ---- k_fused: block 0 = eig (3 sweeps) -> V/LAM -> flagV;
// blocks 1..nRng = RNG producer; blocks nRng+1..nRng+8 = setup2 (AMU,F) ->
// flagF, then poll(flagF==8 && flagV) -> fz / VF pack / wconst (parallel).
#define EP 65
__global__ __launch_bounds__(1024) void k_fused(float* __restrict__ ws, KParams P,
                                                int nRng, int nS, int Lcut) {
  const int blk = blockIdx.x;
  const int tid = threadIdx.x;
  if (blk == 0) {
    // ---- cyclic Jacobi, 3 sweeps x 63 rounds, pitch 65 (r18 arithmetic)
    __shared__ float Am[64 * EP];
    __shared__ float Vm[64 * EP];
    __shared__ float cs_c[32], cs_s[32];
    __shared__ int ppu[32], ppv[32];
    for (int i = tid; i < 4096; i += 1024) {
      int r = i >> 6, c = i & 63;
      Am[r*EP + c] = ws[WS_A + i];
      Vm[r*EP + c] = (r == c) ? 1.0f : 0.0f;
    }
    const int pA = tid & 31;
    int uA = (pA == 0) ? 0 : pA;
    int vA = (pA == 0) ? 63 : (63 - pA);
    const int pV0 = tid >> 6;
    int uV0 = (pV0 == 0) ? 0 : pV0;
    int vV0 = (pV0 == 0) ? 63 : (63 - pV0);
    const int pV1 = 16 + pV0;
    int uV1 = pV1;
    int vV1 = 63 - pV1;
    __syncthreads();
    for (int sweep = 0; sweep < 3; ++sweep) {
      for (int r = 0; r < 63; ++r) {
        if (tid < 32) {
          float app = Am[uA*(EP+1)], aqq = Am[vA*(EP+1)], apq = Am[uA*EP+vA];
          float c = 1.0f, s = 0.0f;
          if (fabsf(apq) > 1e-30f) {
            float tau = (aqq - app) / (2.0f * apq);
            float t = copysignf(1.0f / (fabsf(tau) + sqrtf(fmaf(tau, tau, 1.0f))), tau);
            c = 1.0f / sqrtf(fmaf(t, t, 1.0f));
            s = t * c;
          }
          ppu[tid] = uA; ppv[tid] = vA; cs_c[tid] = c; cs_s[tid] = s;
        }
        __syncthreads();
        {
          int i = tid >> 5;
          int ui = ppu[i], vi = ppv[i];
          const int uj = uA, vj = vA;
          float ci = cs_c[i], si = cs_s[i], cj = cs_c[pA], sj = cs_s[pA];
          float a = Am[ui*EP+uj], bb = Am[ui*EP+vj];
          float d = Am[vi*EP+uj], e  = Am[vi*EP+vj];
          float r0u = ci*a  - si*d;
          float r1u = fmaf(si, a,  ci*d);
          float r0v = ci*bb - si*e;
          float r1v = fmaf(si, bb, ci*e);
          Am[ui*EP+uj] = cj*r0u - sj*r0v;
          Am[ui*EP+vj] = fmaf(sj, r0u, cj*r0v);
          Am[vi*EP+uj] = cj*r1u - sj*r1v;
          Am[vi*EP+vj] = fmaf(sj, r1u, cj*r1v);
        }
        {
          const int k = tid & 63;
          {
            float c2 = cs_c[pV0], s2 = cs_s[pV0];
            float vu = Vm[k*EP+uV0], vv = Vm[k*EP+vV0];
            Vm[k*EP+uV0] = c2*vu - s2*vv;
            Vm[k*EP+vV0] = fmaf(s2, vu, c2*vv);
          }
          {
            float c2 = cs_c[pV1], s2 = cs_s[pV1];
            float vu = Vm[k*EP+uV1], vv = Vm[k*EP+vV1];
            Vm[k*EP+uV1] = c2*vu - s2*vv;
            Vm[k*EP+vV1] = fmaf(s2, vu, c2*vv);
          }
        }
        uA  = (uA  == 0) ? 0 : ((uA  == 63) ? 1 : uA  + 1);
        vA  = (vA  == 63) ? 1 : vA  + 1;
        uV0 = (uV0 == 0) ? 0 : ((uV0 == 63) ? 1 : uV0 + 1);
        vV0 = (vV0 == 63) ? 1 : vV0 + 1;
        uV1 = (uV1 == 63) ? 1 : uV1 + 1;
        vV1 = (vV1 == 63) ? 1 : vV1 + 1;
        __syncthreads();
      }
    }
    for (int i = tid; i < 4096; i += 1024) ws[WS_V + i] = Vm[(i >> 6)*EP + (i & 63)];
    if (tid < 64) ws[WS_LAM + tid] = Am[tid*(EP+1)];
    __threadfence();
    __syncthreads();
    if (tid == 0) atomicAdd((int*)ws + WS_FLG + 1, 1);   // flagV
  } else if (blk <= nRng) {
    // ---- RNG producer: exact k_main DRAW+SPLIT, packed f16hi|f16lo u32,
    // step-major layout. Threads L < Lcut stage one extra (fractional) step.
    const int L = (blk - 1) * 1024 + tid;
    const int bI = L >> 8, t256 = L & 255;
    const int wv = t256 >> 6, lane = t256 & 63;
    const int cw = lane & 15, g4 = lane >> 4;
    const int koff = g4 * 8;
    const int trajBase = bI * 64 + wv * 16;
    const uint32_t base = (uint32_t)(trajBase + cw) * 64u;
    uint32_t* wsu = (uint32_t*)ws;
    const int nSteps = nS + ((nS < 16 && L < Lcut) ? 1 : 0);
    for (int j = 1; j <= nSteps; ++j) {
      const uint32_t k0 = P.fk0[j-1], k1 = P.fk1[j-1];
      uint32_t ov[16];
#pragma unroll
      for (int i = 0; i < 8; ++i) { float dd; DRAW(dd, koff + i) PACKD(ov[i], dd) }
#pragma unroll
      for (int i = 0; i < 8; ++i) { float dd; DRAW(dd, 32 + koff + i) PACKD(ov[8+i], dd) }
      uint4_t* wr = (uint4_t*)(wsu + WS_RNG + (size_t)(j-1)*STEP_U32 + (size_t)L*16u);
      wr[0] = (uint4_t){ov[0], ov[1], ov[2], ov[3]};
      wr[1] = (uint4_t){ov[4], ov[5], ov[6], ov[7]};
      wr[2] = (uint4_t){ov[8], ov[9], ov[10], ov[11]};
      wr[3] = (uint4_t){ov[12], ov[13], ov[14], ov[15]};
    }
  } else {
    // ---- setup2 + tails. sblk in [0,8): first AMU/F (1 elem/thread), then
    // after flagF==8 && flagV: fz (1 elem/thread), VF pack (sblk 0),
    // wconst (sblk 1). All expressions identical to r22's kernels.
    const int sblk = blk - 1 - nRng;
    int t = sblk * 1024 + tid;
    {
      int b = t >> 6, d = t & 63;
      float s = 0;
      for (int m = 0; m < 64; ++m) s = fmaf(ws[WS_MU + b*64+m], ws[WS_A + m*64+d], s);
      ws[WS_AMU + t] = s;
      ws[WS_F + t] = ws[WS_C + t] - ws[WS_MU + t] - s;
    }
    __threadfence();
    __syncthreads();
    if (tid == 0) {
      atomicAdd((int*)ws + WS_FLG, 1);                   // flagF
      while (atomicAdd((int*)ws + WS_FLG, 0) < 8 ||
             atomicAdd((int*)ws + WS_FLG + 1, 0) < 1) { }
    }
    __syncthreads();
    __threadfence();
    // fz = F V (same loop order as old setupfv)
    {
      int b = t >> 6, d = t & 63;
      float s = 0;
      for (int m = 0; m < 64; ++m) s = fmaf(ws[WS_F + b*64+m], ws[WS_V + m*64+d], s);
      ws[WS_FZ + t] = s;
    }
    if (sblk == 0) {
      // pack V into f16 hi/lo MFMA B-fragments (identical layout/rounding)
      int idx = tid;                     // 0..1023
      int lane = idx & 63, Fr = idx >> 6;
      int tt = Fr >> 3, kt = (Fr >> 2) & 1, nt = Fr & 3;
      int n = nt*16 + (lane & 15);
      int k0 = kt*32 + ((lane >> 4) & 3)*8;
      uint32_t out[4];
      for (int jj = 0; jj < 4; ++jj) {
        float v0 = ws[WS_V + (k0 + 2*jj    )*64 + n];
        float v1 = ws[WS_V + (k0 + 2*jj + 1)*64 + n];
        _Float16 h0, h1;
        if (tt == 0) { h0 = (_Float16)v0; h1 = (_Float16)v1; }
        else {
          _Float16 a0 = (_Float16)v0, a1 = (_Float16)v1;
          h0 = (_Float16)(v0 - (float)a0);
          h1 = (_Float16)(v1 - (float)a1);
        }
        unsigned short u0 = __builtin_bit_cast(unsigned short, h0);
        unsigned short u1 = __builtin_bit_cast(unsigned short, h1);
        out[jj] = (uint32_t)u0 | ((uint32_t)u1 << 16);
      }
      uint32_t* dst = (uint32_t*)ws + WS_VF + idx*4;
      dst[0] = out[0]; dst[1] = out[1]; dst[2] = out[2]; dst[3] = out[3];
    } else if (sblk == 1 && tid < 128) {
      int b = tid;
      float muc = 0, musq = 0, muamu = 0;
      for (int d = 0; d < 64; ++d) {
        float m = ws[WS_MU + b*64+d];
        muc   = fmaf(m, ws[WS_C + b*64+d], muc);
        musq  = fmaf(m, m, musq);
        muamu = fmaf(m, ws[WS_AMU + b*64+d], muamu);
      }
      ws[WS_WC + b] = -32.0f * LOG2PI - 0.5f * ws[WS_XSQ + b]
                      + muc - 0.5f * musq - 0.5f * muamu;
    }
  }
}

// ---- k_main hot-loop macros ------------------------------------------------

#define SPLIT1(AH, AL, J, VV)                                                \
  { _Float16 hh = (_Float16)(VV); AH[J] = hh;                                \
    AL[J] = (_Float16)((VV) - (float)hh); }

#define DRAWSPLIT8(AH, AL, KB)                                               \
  { float dd;                                                                \
    DRAW(dd, (KB)+0) SPLIT1(AH, AL, 0, dd)                                   \
    DRAW(dd, (KB)+1) SPLIT1(AH, AL, 1, dd)                                   \
    DRAW(dd, (KB)+2) SPLIT1(AH, AL, 2, dd)                                   \
    DRAW(dd, (KB)+3) SPLIT1(AH, AL, 3, dd)                                   \
    DRAW(dd, (KB)+4) SPLIT1(AH, AL, 4, dd)                                   \
    DRAW(dd, (KB)+5) SPLIT1(AH, AL, 5, dd)                                   \
    DRAW(dd, (KB)+6) SPLIT1(AH, AL, 6, dd)                                   \
    DRAW(dd, (KB)+7) SPLIT1(AH, AL, 7, dd) }

#define FRAGB(T, KT, NT)                                                     \
  __builtin_bit_cast(half8_t, VF[(((T)*2+(KT))*4+(NT))*64 + lane])

#define ROT1(ZO, NT, AH0, AL0, AH1, AL1)                                     \
  { half8_t bh0 = FRAGB(0,0,NT), bh1 = FRAGB(0,1,NT);                        \
    half8_t bl0 = FRAGB(1,0,NT), bl1 = FRAGB(1,1,NT);                        \
    f4_t aa = {0.f, 0.f, 0.f, 0.f};                                          \
    aa = __builtin_amdgcn_mfma_f32_16x16x32_f16(AH0, bh0, aa, 0, 0, 0);      \
    aa = __builtin_amdgcn_mfma_f32_16x16x32_f16(AH1, bh1, aa, 0, 0, 0);      \
    aa = __builtin_amdgcn_mfma_f32_16x16x32_f16(AL0, bh0, aa, 0, 0, 0);      \
    aa = __builtin_amdgcn_mfma_f32_16x16x32_f16(AL1, bh1, aa, 0, 0, 0);      \
    aa = __builtin_amdgcn_mfma_f32_16x16x32_f16(AH0, bl0, aa, 0, 0, 0);      \
    aa = __builtin_amdgcn_mfma_f32_16x16x32_f16(AH1, bl1, aa, 0, 0, 0);      \
    ZO = aa; }

#define ROTATE4(O0, O1, O2, O3, AH0, AL0, AH1, AL1)                          \
  ROT1(O0, 0, AH0, AL0, AH1, AL1) ROT1(O1, 1, AH0, AL0, AH1, AL1)            \
  ROT1(O2, 2, AH0, AL0, AH1, AL1) ROT1(O3, 3, AH0, AL0, AH1, AL1)

// vectorized leapfrog: v_pk_fma_f32 path, IEEE-identical per component
#define LF4V(ZV, PV, NLM, FV, DBL)                                           \
  { f4_t gg = __builtin_elementwise_fma(bk4,                                 \
        __builtin_elementwise_fma(NLM, ZV, FV), -ZV);                        \
    PV = __builtin_elementwise_fma(c025v, gg, PV);                           \
    if (DBL) PV = __builtin_elementwise_fma(c025v, gg, PV);                  \
    ZV = __builtin_elementwise_fma(c005v, PV, ZV); }
#define SUBSTEPV(DBL)                                                        \
  LF4V(z0, pz0, nlm0, fzv0, DBL) LF4V(z1, pz1, nlm1, fzv1, DBL)              \
  LF4V(z2, pz2, nlm2, fzv2, DBL) LF4V(z3, pz3, nlm3, fzv3, DBL)

#define W_EVALN(WOUT)                                                        \
  { f4_t s1 = fzv0*z0 + fzv1*z1 + fzv2*z2 + fzv3*z3;                         \
    f4_t s2 = (lmS0*z0)*z0 + (lmS1*z1)*z1 + (lmS2*z2)*z2 + (lmS3*z3)*z3;     \
    f4_t vv = s1 - 0.5f*s2;                                                  \
    float r0 = vv.x, r1 = vv.y, r2 = vv.z, r3 = vv.w;                        \
    r0 += __shfl_xor(r0, 1); r1 += __shfl_xor(r1, 1);                        \
    r2 += __shfl_xor(r2, 1); r3 += __shfl_xor(r3, 1);                        \
    r0 += __shfl_xor(r0, 2); r1 += __shfl_xor(r1, 2);                        \
    r2 += __shfl_xor(r2, 2); r3 += __shfl_xor(r3, 2);                        \
    r0 += __shfl_xor(r0, 4); r1 += __shfl_xor(r1, 4);                        \
    r2 += __shfl_xor(r2, 4); r3 += __shfl_xor(r3, 4);                        \
    r0 += __shfl_xor(r0, 8); r1 += __shfl_xor(r1, 8);                        \
    r2 += __shfl_xor(r2, 8); r3 += __shfl_xor(r3, 8);                        \
    float wsel = (cw == 0) ? r0 : ((cw == 1) ? r1 : ((cw == 2) ? r2 : r3));  \
    WOUT = wsel + wcs; }

#define PLO 0x05040100u
#define PHI 0x07060302u

// ---- main: MFMA rotation; wave = 16 trajs; 4 waves/block, 2048 blocks.
__global__ __launch_bounds__(256) void k_main(const float* __restrict__ qn,
                                              const float* __restrict__ ws,
                                              float* __restrict__ slw_out,
                                              KParams P, int nS, int Lcut) {
  __shared__ uint4_t VF[1024];   // 16 KB: V f16 hi/lo B-fragments
  const int tid = threadIdx.x;
  {
    const uint4_t* src = (const uint4_t*)((const uint32_t*)ws + WS_VF);
    for (int i = tid; i < 1024; i += 256) VF[i] = src[i];
  }
  __syncthreads();

  const int lane = tid & 63;
  const int wv = tid >> 6;
  const int cw = lane & 15;              // MFMA col; also A-operand row m
  const int g4 = lane >> 4;              // quad id
  const int koff = g4 * 8;               // A-fragment k offset
  const int trajBase = blockIdx.x * 64 + wv * 16;
  const uint32_t base = (uint32_t)(trajBase + cw) * 64u;   // RNG row base
  const int Lme = blockIdx.x * 256 + tid;                  // staged-RNG row

  const int b0 = (trajBase + g4*4 + 0) & 127;
  const int b1 = (trajBase + g4*4 + 1) & 127;
  const int b2 = (trajBase + g4*4 + 2) & 127;
  const int b3 = (trajBase + g4*4 + 3) & 127;
  f4_t fzv0, fzv1, fzv2, fzv3;
  fzv0.x = ws[WS_FZ + b0*64 + cw];      fzv0.y = ws[WS_FZ + b1*64 + cw];
  fzv0.z = ws[WS_FZ + b2*64 + cw];      fzv0.w = ws[WS_FZ + b3*64 + cw];
  fzv1.x = ws[WS_FZ + b0*64 + 16 + cw]; fzv1.y = ws[WS_FZ + b1*64 + 16 + cw];
  fzv1.z = ws[WS_FZ + b2*64 + 16 + cw]; fzv1.w = ws[WS_FZ + b3*64 + 16 + cw];
  fzv2.x = ws[WS_FZ + b0*64 + 32 + cw]; fzv2.y = ws[WS_FZ + b1*64 + 32 + cw];
  fzv2.z = ws[WS_FZ + b2*64 + 32 + cw]; fzv2.w = ws[WS_FZ + b3*64 + 32 + cw];
  fzv3.x = ws[WS_FZ + b0*64 + 48 + cw]; fzv3.y = ws[WS_FZ + b1*64 + 48 + cw];
  fzv3.z = ws[WS_FZ + b2*64 + 48 + cw]; fzv3.w = ws[WS_FZ + b3*64 + 48 + cw];
  const float lmS0 = ws[WS_LAM + cw];
  const float lmS1 = ws[WS_LAM + 16 + cw];
  const float lmS2 = ws[WS_LAM + 32 + cw];
  const float lmS3 = ws[WS_LAM + 48 + cw];
  const float wcs = ws[WS_WC + ((trajBase + g4*4 + (cw & 3)) & 127)];
  const f4_t nlm0 = {-lmS0, -lmS0, -lmS0, -lmS0};
  const f4_t nlm1 = {-lmS1, -lmS1, -lmS1, -lmS1};
  const f4_t nlm2 = {-lmS2, -lmS2, -lmS2, -lmS2};
  const f4_t nlm3 = {-lmS3, -lmS3, -lmS3, -lmS3};
  const f4_t c025v = {0.025f, 0.025f, 0.025f, 0.025f};
  const f4_t c005v = {0.05f, 0.05f, 0.05f, 0.05f};

  f4_t z0, z1, z2, z3, pz0, pz1, pz2, pz3;
  float slw = 0.0f;

  // j = 0: z0 = qn . V  (qn read at A-fragment positions; f16 3-term split)
  {
    const float* qp = qn + (size_t)base;
    f4_t qa = *(const f4_t*)(qp + koff);
    f4_t qb = *(const f4_t*)(qp + koff + 4);
    f4_t qc = *(const f4_t*)(qp + 32 + koff);
    f4_t qd = *(const f4_t*)(qp + 32 + koff + 4);
    half8_t ah0, al0, ah1, al1;
    SPLIT1(ah0, al0, 0, qa.x) SPLIT1(ah0, al0, 1, qa.y)
    SPLIT1(ah0, al0, 2, qa.z) SPLIT1(ah0, al0, 3, qa.w)
    SPLIT1(ah0, al0, 4, qb.x) SPLIT1(ah0, al0, 5, qb.y)
    SPLIT1(ah0, al0, 6, qb.z) SPLIT1(ah0, al0, 7, qb.w)
    SPLIT1(ah1, al1, 0, qc.x) SPLIT1(ah1, al1, 1, qc.y)
    SPLIT1(ah1, al1, 2, qc.z) SPLIT1(ah1, al1, 3, qc.w)
    SPLIT1(ah1, al1, 4, qd.x) SPLIT1(ah1, al1, 5, qd.y)
    SPLIT1(ah1, al1, 6, qd.z) SPLIT1(ah1, al1, 7, qd.w)
    ROTATE4(z0, z1, z2, z3, ah0, al0, ah1, al1)
  }
  {
    float w0;
    W_EVALN(w0);
    slw = fmaf(P.dbeta[0], w0, slw);
  }

  for (int j = 1; j <= 16; ++j) {
    const float bk = P.beta[j];
    const f4_t bk4 = {bk, bk, bk, bk};
    half8_t ah0, al0, ah1, al1;
    if (j <= nS || (j == nS + 1 && Lme < Lcut)) {
      // staged: load packed f16hi|f16lo draws (step-major), unpack via v_perm
      const uint32_t* rp = (const uint32_t*)ws + WS_RNG
                         + (size_t)(j-1)*STEP_U32 + (size_t)Lme*16u;
      const uint4_t* rr = (const uint4_t*)rp;
      uint4_t q0 = rr[0], q1 = rr[1], q2 = rr[2], q3 = rr[3];
      uint4_t uh0 = { __builtin_amdgcn_perm(q0.y, q0.x, PLO),
                      __builtin_amdgcn_perm(q0.w, q0.z, PLO),
                      __builtin_amdgcn_perm(q1.y, q1.x, PLO),
                      __builtin_amdgcn_perm(q1.w, q1.z, PLO) };
      uint4_t ul0 = { __builtin_amdgcn_perm(q0.y, q0.x, PHI),
                      __builtin_amdgcn_perm(q0.w, q0.z, PHI),
                      __builtin_amdgcn_perm(q1.y, q1.x, PHI),
                      __builtin_amdgcn_perm(q1.w, q1.z, PHI) };
      uint4_t uh1 = { __builtin_amdgcn_perm(q2.y, q2.x, PLO),
                      __builtin_amdgcn_perm(q2.w, q2.z, PLO),
                      __builtin_amdgcn_perm(q3.y, q3.x, PLO),
                      __builtin_amdgcn_perm(q3.w, q3.z, PLO) };
      uint4_t ul1 = { __builtin_amdgcn_perm(q2.y, q2.x, PHI),
                      __builtin_amdgcn_perm(q2.w, q2.z, PHI),
                      __builtin_amdgcn_perm(q3.y, q3.x, PHI),
                      __builtin_amdgcn_perm(q3.w, q3.z, PHI) };
      ah0 = __builtin_bit_cast(half8_t, uh0);
      al0 = __builtin_bit_cast(half8_t, ul0);
      ah1 = __builtin_bit_cast(half8_t, uh1);
      al1 = __builtin_bit_cast(half8_t, ul1);
    } else {
      const uint32_t k0 = P.fk0[j-1], k1 = P.fk1[j-1];
      DRAWSPLIT8(ah0, al0, koff)
      DRAWSPLIT8(ah1, al1, 32 + koff)
    }
    ROTATE4(pz0, pz1, pz2, pz3, ah0, al0, ah1, al1)   // pz = p . V
    SUBSTEPV(false)
    SUBSTEPV(true)
    SUBSTEPV(true)
    float wj;
    W_EVALN(wj);
    slw = fmaf(P.dbeta[j], wj, slw);
  }
  if (cw < 4) slw_out[trajBase + g4*4 + cw] = slw;
}

// ---- logsumexp over n per batch column b
__global__ void k_reduce(const float* __restrict__ slw, float* __restrict__ out) {
  __shared__ float red[256];
  int b = blockIdx.x, t = threadIdx.x;
  float v0 = slw[t*128 + b];
  float v1 = slw[(t+256)*128 + b];
  float v2 = slw[(t+512)*128 + b];
  float v3 = slw[(t+768)*128 + b];
  float m = fmaxf(fmaxf(v0, v1), fmaxf(v2, v3));
  red[t] = m; __syncthreads();
  for (int s = 128; s > 0; s >>= 1) {
    if (t < s) red[t] = fmaxf(red[t], red[t+s]);
    __syncthreads();
  }
  m = red[0]; __syncthreads();
  float sum = expf(v0 - m) + expf(v1 - m) + expf(v2 - m) + expf(v3 - m);
  red[t] = sum; __syncthreads();
  for (int s = 128; s > 0; s >>= 1) {
    if (t < s) red[t] += red[t+s];
    __syncthreads();
  }
  if (t == 0) out[b] = m + logf(red[0]) - 6.93147180559945309f;  // - log(1024)
}

extern "C" void kernel_launch(void* const* d_in, const int* in_sizes, int n_in,
                              void* d_out, int out_size, void* d_ws, size_t ws_size,
                              hipStream_t stream) {
  const float* x    = (const float*)d_in[0];
  const float* Wenc = (const float*)d_in[1];
  const float* Wdec = (const float*)d_in[2];
  const float* qn   = (const float*)d_in[3];
  // d_in[4] (p_noise) is dead (momentum fully resampled) but NOT used for
  // staging: dirtying an input costs ~20us harness re-poison (r23).
  float* ws  = (float*)d_ws;
  float* out = (float*)d_out;
  if (ws_size < (size_t)WS_TOTAL * sizeof(float)) return;

  // staged-RNG step count from available workspace (33.55 MB per step),
  // plus fractional staging of the next step with the leftover.
  size_t avail_u32 = ws_size / 4;
  int nS = 0, Lcut = 0;
  if (avail_u32 > (size_t)WS_RNG) {
    size_t r = avail_u32 - (size_t)WS_RNG;
    nS = (int)(r / STEP_U32);
    if (nS > 16) nS = 16;
    if (nS < 16) {
      size_t rem = r - (size_t)nS * STEP_U32;
      size_t lc = (rem / 16) & ~(size_t)63;       // wave-aligned thread count
      if (lc > 524288) lc = 524288;
      Lcut = (int)lc;
    }
  }
  const int nRng = (nS > 0 || Lcut > 0) ? 512 : 0;

  KParams P;
  double bb[18];
  for (int i = 0; i < 18; ++i) {
    double tt = (double)i / 17.0;
    bb[i] = 1.0 / (1.0 + exp(-(8.0 * tt - 4.0)));
  }
  for (int i = 0; i < 18; ++i) P.beta[i] = (float)((bb[i] - bb[0]) / (bb[17] - bb[0]));
  for (int j = 0; j <= 16; ++j) P.dbeta[j] = P.beta[j+1] - P.beta[j];
  for (int k = 1; k <= 16; ++k) {
    uint32_t a, c;
    threefry2x32(0u, 42u, 0u, (uint32_t)k, a, c);  // fold_in(key(42), k)
    P.fk0[k-1] = a; P.fk1[k-1] = c;
  }

  hipLaunchKernelGGL(k_setup1, dim3(81), dim3(256), 0, stream, x, Wenc, Wdec, ws);
  hipLaunchKernelGGL(k_fused, dim3(1 + nRng + 8), dim3(1024), 0, stream, ws, P, nRng, nS, Lcut);
  hipLaunchKernelGGL(k_main, dim3(2048), dim3(256), 0, stream, qn, ws, ws + WS_SLW, P, nS, Lcut);
  hipLaunchKernelGGL(k_reduce, dim3(128), dim3(256), 0, stream, ws + WS_SLW, out);
}